// Round 8
// baseline (293.107 us; speedup 1.0000x reference)
//
#include <hip/hip_runtime.h>
#include <hip/hip_bf16.h>

// TinySelfAttention: x[2,2048,1024] fp32; Wq/Wk/Wv/Wo [1024,1024] fp32 ([out,in]).
// out = softmax_causal((xWq^T)(xWk^T)^T/8) (xWv^T) Wo^T, fp32.
//
// Pipeline: cast x -> bf16, cast 4 W -> bf16 (one kernel, contiguous dest) |
//           fused QKV MFMA GEMM (128^2 tile, global_load_lds) -> qkv[row][3072] |
//           bf16 MFMA flash attention (1 q-tile/block, 1024 blocks) -> y bf16 |
//           MFMA GEMM y@Wo^T -> fp32 out.

#define S_LEN  2048
#define BATCH  2
#define DMODEL 1024
#define NHEADS 16
#define HDIM   64
#define QKV_LD 3072

typedef short short8 __attribute__((ext_vector_type(8)));
typedef float f32x4  __attribute__((ext_vector_type(4)));

__device__ __forceinline__ float b2f(unsigned short u) {
    union { unsigned int i; float f; } x; x.i = ((unsigned int)u) << 16; return x.f;
}
__device__ __forceinline__ unsigned short f2b(float f) {
    union { float f; unsigned int i; } x; x.f = f;
    unsigned int r = x.i + 0x7fffu + ((x.i >> 16) & 1u);  // RNE
    return (unsigned short)(r >> 16);
}

// async global->LDS, 16B per lane; LDS dest = wave-uniform base + lane*16 (HW rule)
__device__ __forceinline__ void gload16(const unsigned short* g, unsigned short* l) {
    __builtin_amdgcn_global_load_lds(
        (const __attribute__((address_space(1))) unsigned int*)g,
        (__attribute__((address_space(3))) unsigned int*)l, 16, 0, 0);
}

// XOR-swizzled accessor for 128B-row LDS tiles (attn; G4 bank-conflict fix).
__device__ __forceinline__ unsigned short* swzp(unsigned short* base, int row, int col) {
    int byte = (col << 1) ^ ((((row >> 3) ^ row) & 7) << 4);
    return base + (row << 6) + (byte >> 1);
}

// ---------------- cast fp32 -> bf16, 4 elems/thread ----------------
__global__ void cast_kernel(const float* __restrict__ in, unsigned short* __restrict__ out, int n4) {
    int i = blockIdx.x * blockDim.x + threadIdx.x;
    if (i >= n4) return;
    float4 v = ((const float4*)in)[i];
    unsigned int lo = (unsigned int)f2b(v.x) | ((unsigned int)f2b(v.y) << 16);
    unsigned int hi = (unsigned int)f2b(v.z) | ((unsigned int)f2b(v.w) << 16);
    ((uint2*)out)[i] = make_uint2(lo, hi);
}

// cast 4 weights (1M floats each) into one contiguous bf16 dest (wqkv | wo)
__global__ void cast_w4(const float* __restrict__ w0, const float* __restrict__ w1,
                        const float* __restrict__ w2, const float* __restrict__ w3,
                        unsigned short* __restrict__ out) {
    int i = blockIdx.x * blockDim.x + threadIdx.x;     // over 4M/4 = 1M float4
    if (i >= (1 << 20)) return;
    int seg = i >> 18;                                 // 2^18 float4 per weight
    const float* src = seg == 0 ? w0 : seg == 1 ? w1 : seg == 2 ? w2 : w3;
    float4 v = ((const float4*)src)[i & 0x3FFFF];
    unsigned int lo = (unsigned int)f2b(v.x) | ((unsigned int)f2b(v.y) << 16);
    unsigned int hi = (unsigned int)f2b(v.z) | ((unsigned int)f2b(v.w) << 16);
    ((uint2*)out)[i] = make_uint2(lo, hi);
}

// ---------------- bf16 MFMA GEMM: C[M,N] = A[M,K] @ W[N,K]^T ----------------
// m97 structure: 128x128 tile, BK=64, 256 threads (4 waves, 2x2 of 64x64),
// linear LDS + global_load_lds(16B), 2-barrier loop.
template<int OUT_BF16>
__global__ __launch_bounds__(256) void gemm128(const unsigned short* __restrict__ A,
                                               const unsigned short* __restrict__ W,
                                               unsigned short* __restrict__ Cb,
                                               float* __restrict__ Cf,
                                               int N, int K) {
    __shared__ unsigned short As[128 * 64];
    __shared__ unsigned short Bs[128 * 64];
    const int tid  = threadIdx.x;
    const int lane = tid & 63;
    const int wave = tid >> 6;
    const int bm = blockIdx.y * 128;
    const int bn = blockIdx.x * 128;
    const int wr = (wave >> 1) * 64;
    const int wc = (wave & 1) * 64;
    const int l15 = lane & 15;
    const int l4  = lane >> 4;

    // staging: wave w covers tile rows [w*32, w*32+32), 4 instrs x 8 rows each;
    // lane l -> row l>>3, col (l&7)*8 shorts (matches linear LDS base+lane*16B)
    const int srow = wave * 32 + (lane >> 3);
    const int scol = (lane & 7) * 8;
    const unsigned short* Ag = A + (size_t)(bm + srow) * K + scol;
    const unsigned short* Wg = W + (size_t)(bn + srow) * K + scol;
    unsigned short* Al = As + wave * 32 * 64;
    unsigned short* Bl = Bs + wave * 32 * 64;

    f32x4 acc[4][4];
#pragma unroll
    for (int i = 0; i < 4; ++i)
#pragma unroll
        for (int j = 0; j < 4; ++j) acc[i][j] = (f32x4){0.f, 0.f, 0.f, 0.f};

    for (int k0 = 0; k0 < K; k0 += 64) {
        __syncthreads();   // previous iteration's ds_reads done
#pragma unroll
        for (int i = 0; i < 4; ++i) {
            gload16(Ag + k0 + (size_t)(i * 8) * K, Al + i * 8 * 64);
            gload16(Wg + k0 + (size_t)(i * 8) * K, Bl + i * 8 * 64);
        }
        __syncthreads();   // drains vmcnt(0): staged data visible
#pragma unroll
        for (int kk = 0; kk < 2; ++kk) {
            short8 af[4], bf[4];
#pragma unroll
            for (int mi = 0; mi < 4; ++mi)
                af[mi] = *(const short8*)&As[(wr + mi * 16 + l15) * 64 + kk * 32 + l4 * 8];
#pragma unroll
            for (int ni = 0; ni < 4; ++ni)
                bf[ni] = *(const short8*)&Bs[(wc + ni * 16 + l15) * 64 + kk * 32 + l4 * 8];
#pragma unroll
            for (int mi = 0; mi < 4; ++mi)
#pragma unroll
                for (int ni = 0; ni < 4; ++ni)
                    acc[mi][ni] = __builtin_amdgcn_mfma_f32_16x16x32_bf16(af[mi], bf[ni], acc[mi][ni], 0, 0, 0);
        }
    }
    // epilogue: C/D layout col=lane&15, row=(lane>>4)*4+i (HW-verified)
#pragma unroll
    for (int mi = 0; mi < 4; ++mi)
#pragma unroll
        for (int ni = 0; ni < 4; ++ni)
#pragma unroll
            for (int i = 0; i < 4; ++i) {
                int row = bm + wr + mi * 16 + l4 * 4 + i;
                int col = bn + wc + ni * 16 + l15;
                float v = acc[mi][ni][i];
                if constexpr (OUT_BF16) Cb[(size_t)row * N + col] = f2b(v);
                else                    Cf[(size_t)row * N + col] = v;
            }
}

// ---------------- bf16 MFMA flash attention (causal) ----------------
// Block = (b, h, q-tile): 1024 blocks (~4/CU), dynamic scheduling balances the
// causal wedge. 4 waves x 16 q-rows; QK^T and PV on mfma_f32_16x16x32_bf16.
// Q/K/V read from interleaved qkv[row][3072]; K, V^T staged in swizzled LDS.
__global__ __launch_bounds__(256) void attn_mfma(const unsigned short* __restrict__ Qp,
                                                 const unsigned short* __restrict__ Kp,
                                                 const unsigned short* __restrict__ Vp,
                                                 unsigned short* __restrict__ Yp) {
    __shared__ unsigned short Ks[64 * 64];     // K[key][d]
    __shared__ unsigned short Vt[64 * 64];     // V^T[d][key]
    __shared__ unsigned short Pl[4 * 16 * 64]; // per-wave P[q][key]
    const int tid  = threadIdx.x;
    const int lane = tid & 63;
    const int wq   = tid >> 6;
    const int l15  = lane & 15;
    const int l4   = lane >> 4;
    const int r    = tid >> 2;
    const int c4   = tid & 3;
    const int qt = blockIdx.x, h = blockIdx.y, b = blockIdx.z;
    unsigned short* Pw = Pl + wq * (16 * 64);

    short8 qf0, qf1;
    {
        const unsigned short* qb = Qp + ((size_t)(b * S_LEN + qt * 64 + wq * 16 + l15)) * QKV_LD
                                      + h * HDIM + l4 * 8;
        qf0 = *(const short8*)qb;
        qf1 = *(const short8*)(qb + 32);
    }
    f32x4 oacc[4];
    float mrow[4], lrow[4];
#pragma unroll
    for (int t = 0; t < 4; ++t) oacc[t] = (f32x4){0.f, 0.f, 0.f, 0.f};
#pragma unroll
    for (int i = 0; i < 4; ++i) { mrow[i] = -1e30f; lrow[i] = 0.f; }

#pragma unroll 1
    for (int kt = 0; kt <= qt; ++kt) {
        __syncthreads();
        {   // stage K tile + transposed V tile
            const size_t gb = ((size_t)(b * S_LEN + kt * 64 + r)) * QKV_LD + h * HDIM + c4 * 16;
            uint4 k0 = *(const uint4*)(Kp + gb);
            uint4 k1 = *(const uint4*)(Kp + gb + 8);
            uint4 v0 = *(const uint4*)(Vp + gb);
            uint4 v1 = *(const uint4*)(Vp + gb + 8);
            *(uint4*)swzp(Ks, r, c4 * 16)     = k0;
            *(uint4*)swzp(Ks, r, c4 * 16 + 8) = k1;
            const unsigned short* vs = (const unsigned short*)&v0;
#pragma unroll
            for (int j = 0; j < 8; ++j) *swzp(Vt, c4 * 16 + j, r) = vs[j];
            vs = (const unsigned short*)&v1;
#pragma unroll
            for (int j = 0; j < 8; ++j) *swzp(Vt, c4 * 16 + 8 + j, r) = vs[j];
        }
        __syncthreads();

        f32x4 sc[4];
#pragma unroll
        for (int t = 0; t < 4; ++t) sc[t] = (f32x4){0.f, 0.f, 0.f, 0.f};
#pragma unroll
        for (int t = 0; t < 4; ++t) {
            short8 kf = *(const short8*)swzp(Ks, t * 16 + l15, l4 * 8);
            sc[t] = __builtin_amdgcn_mfma_f32_16x16x32_bf16(qf0, kf, sc[t], 0, 0, 0);
        }
#pragma unroll
        for (int t = 0; t < 4; ++t) {
            short8 kf = *(const short8*)swzp(Ks, t * 16 + l15, 32 + l4 * 8);
            sc[t] = __builtin_amdgcn_mfma_f32_16x16x32_bf16(qf1, kf, sc[t], 0, 0, 0);
        }
        const bool diag = (kt == qt);
#pragma unroll
        for (int t = 0; t < 4; ++t)
#pragma unroll
            for (int i = 0; i < 4; ++i) {
                float s = sc[t][i] * 0.125f;
                if (diag && (t * 16 + l15 > wq * 16 + l4 * 4 + i)) s = -1e30f;
                sc[t][i] = s;
            }
#pragma unroll
        for (int i = 0; i < 4; ++i) {
            float mx = fmaxf(fmaxf(sc[0][i], sc[1][i]), fmaxf(sc[2][i], sc[3][i]));
            mx = fmaxf(mx, __shfl_xor(mx, 1));
            mx = fmaxf(mx, __shfl_xor(mx, 2));
            mx = fmaxf(mx, __shfl_xor(mx, 4));
            mx = fmaxf(mx, __shfl_xor(mx, 8));
            const float mn = fmaxf(mrow[i], mx);
            const float al = __expf(mrow[i] - mn);
            mrow[i] = mn;
            float ls = 0.f;
#pragma unroll
            for (int t = 0; t < 4; ++t) {
                float p = __expf(sc[t][i] - mn);
                sc[t][i] = p;
                ls += p;
            }
            ls += __shfl_xor(ls, 1);
            ls += __shfl_xor(ls, 2);
            ls += __shfl_xor(ls, 4);
            ls += __shfl_xor(ls, 8);
            lrow[i] = lrow[i] * al + ls;
#pragma unroll
            for (int t = 0; t < 4; ++t) oacc[t][i] *= al;
        }
#pragma unroll
        for (int t = 0; t < 4; ++t)
#pragma unroll
            for (int i = 0; i < 4; ++i)
                *swzp(Pw, l4 * 4 + i, t * 16 + l15) = f2b(sc[t][i]);

        short8 pf0 = *(const short8*)swzp(Pw, l15, l4 * 8);
        short8 pf1 = *(const short8*)swzp(Pw, l15, 32 + l4 * 8);
#pragma unroll
        for (int td = 0; td < 4; ++td) {
            short8 vf = *(const short8*)swzp(Vt, td * 16 + l15, l4 * 8);
            oacc[td] = __builtin_amdgcn_mfma_f32_16x16x32_bf16(pf0, vf, oacc[td], 0, 0, 0);
        }
#pragma unroll
        for (int td = 0; td < 4; ++td) {
            short8 vf = *(const short8*)swzp(Vt, td * 16 + l15, 32 + l4 * 8);
            oacc[td] = __builtin_amdgcn_mfma_f32_16x16x32_bf16(pf1, vf, oacc[td], 0, 0, 0);
        }
    }
    float linv[4];
#pragma unroll
    for (int i = 0; i < 4; ++i) linv[i] = 1.0f / lrow[i];
    unsigned short* yb = Yp + ((size_t)(b * S_LEN + qt * 64 + wq * 16 + l4 * 4)) * DMODEL
                            + h * HDIM + l15;
#pragma unroll
    for (int i = 0; i < 4; ++i)
#pragma unroll
        for (int td = 0; td < 4; ++td)
            yb[(size_t)i * DMODEL + td * 16] = f2b(oacc[td][i] * linv[i]);
}

extern "C" void kernel_launch(void* const* d_in, const int* in_sizes, int n_in,
                              void* d_out, int out_size, void* d_ws, size_t ws_size,
                              hipStream_t stream) {
    (void)in_sizes; (void)n_in; (void)out_size; (void)ws_size;
    const float* x  = (const float*)d_in[0];
    const float* Wq = (const float*)d_in[1];
    const float* Wk = (const float*)d_in[2];
    const float* Wv = (const float*)d_in[3];
    const float* Wo = (const float*)d_in[4];
    float* out = (float*)d_out;

    const size_t nx = (size_t)BATCH * S_LEN * DMODEL;   // 4,194,304
    const size_t nw = (size_t)DMODEL * DMODEL;          // 1,048,576
    char* ws = (char*)d_ws;
    unsigned short* xb    = (unsigned short*)ws; ws += nx * 2;          // 8 MB
    unsigned short* wqkvb = (unsigned short*)ws; ws += nw * 3 * 2;      // 6 MB (Wq|Wk|Wv rows)
    unsigned short* wob   = (unsigned short*)ws; ws += nw * 2;          // 2 MB (contiguous after wqkvb)
    unsigned short* qkv   = (unsigned short*)ws; ws += nx * 3 * 2;      // 24 MB [row][3072]
    unsigned short* yb    = (unsigned short*)ws; ws += nx * 2;          // 8 MB  -> 48 MB total

    cast_kernel<<<(int)(nx / 4 + 255) / 256, 256, 0, stream>>>(x, xb, (int)(nx / 4));
    cast_w4<<<(1 << 20) / 256, 256, 0, stream>>>(Wq, Wk, Wv, Wo, wqkvb);  // dest = wqkv|wo

    dim3 gq(QKV_LD / 128, (BATCH * S_LEN) / 128);   // 24 x 32
    gemm128<1><<<gq, 256, 0, stream>>>(xb, wqkvb, qkv, nullptr, QKV_LD, DMODEL);

    dim3 ga(S_LEN / 64, NHEADS, BATCH);             // 32 x 16 x 2 = 1024 blocks
    attn_mfma<<<ga, 256, 0, stream>>>(qkv, qkv + DMODEL, qkv + 2 * DMODEL, yb);

    dim3 go(DMODEL / 128, (BATCH * S_LEN) / 128);   // 8 x 32
    gemm128<0><<<go, 256, 0, stream>>>(yb, wob, nullptr, out, DMODEL, DMODEL);
}

// Round 9
// 291.902 us; speedup vs baseline: 1.0041x; 1.0041x over previous
//
#include <hip/hip_runtime.h>
#include <hip/hip_bf16.h>

// TinySelfAttention: x[2,2048,1024] fp32; Wq/Wk/Wv/Wo [1024,1024] fp32 ([out,in]).
// out = softmax_causal((xWq^T)(xWk^T)^T/8) (xWv^T) Wo^T, fp32.
//
// Pipeline: cast x -> bf16, cast 4 W -> bf16 (one kernel, contiguous dest) |
//           fused QKV MFMA GEMM (128^2 tile, global_load_lds) -> qkv[row][3072] |
//           bf16 MFMA flash attention (1 q-tile/block, longest-first) -> y bf16 |
//           MFMA GEMM y@Wo^T -> fp32 out.

#define S_LEN  2048
#define BATCH  2
#define DMODEL 1024
#define NHEADS 16
#define HDIM   64
#define QKV_LD 3072

typedef short short8 __attribute__((ext_vector_type(8)));
typedef float f32x4  __attribute__((ext_vector_type(4)));

__device__ __forceinline__ float b2f(unsigned short u) {
    union { unsigned int i; float f; } x; x.i = ((unsigned int)u) << 16; return x.f;
}
__device__ __forceinline__ unsigned short f2b(float f) {
    union { float f; unsigned int i; } x; x.f = f;
    unsigned int r = x.i + 0x7fffu + ((x.i >> 16) & 1u);  // RNE
    return (unsigned short)(r >> 16);
}

// async global->LDS, 16B per lane; LDS dest = wave-uniform base + lane*16 (HW rule)
__device__ __forceinline__ void gload16(const unsigned short* g, unsigned short* l) {
    __builtin_amdgcn_global_load_lds(
        (const __attribute__((address_space(1))) unsigned int*)g,
        (__attribute__((address_space(3))) unsigned int*)l, 16, 0, 0);
}

// XOR-swizzled accessor for 128B-row LDS tiles (attn; G4 bank-conflict fix).
__device__ __forceinline__ unsigned short* swzp(unsigned short* base, int row, int col) {
    int byte = (col << 1) ^ ((((row >> 3) ^ row) & 7) << 4);
    return base + (row << 6) + (byte >> 1);
}

// ---------------- cast fp32 -> bf16, 4 elems/thread ----------------
__global__ void cast_kernel(const float* __restrict__ in, unsigned short* __restrict__ out, int n4) {
    int i = blockIdx.x * blockDim.x + threadIdx.x;
    if (i >= n4) return;
    float4 v = ((const float4*)in)[i];
    unsigned int lo = (unsigned int)f2b(v.x) | ((unsigned int)f2b(v.y) << 16);
    unsigned int hi = (unsigned int)f2b(v.z) | ((unsigned int)f2b(v.w) << 16);
    ((uint2*)out)[i] = make_uint2(lo, hi);
}

// cast 4 weights (1M floats each) into one contiguous bf16 dest (wqkv | wo)
__global__ void cast_w4(const float* __restrict__ w0, const float* __restrict__ w1,
                        const float* __restrict__ w2, const float* __restrict__ w3,
                        unsigned short* __restrict__ out) {
    int i = blockIdx.x * blockDim.x + threadIdx.x;     // over 4M/4 = 1M float4
    if (i >= (1 << 20)) return;
    int seg = i >> 18;                                 // 2^18 float4 per weight
    const float* src = seg == 0 ? w0 : seg == 1 ? w1 : seg == 2 ? w2 : w3;
    float4 v = ((const float4*)src)[i & 0x3FFFF];
    unsigned int lo = (unsigned int)f2b(v.x) | ((unsigned int)f2b(v.y) << 16);
    unsigned int hi = (unsigned int)f2b(v.z) | ((unsigned int)f2b(v.w) << 16);
    ((uint2*)out)[i] = make_uint2(lo, hi);
}

// ---------------- bf16 MFMA GEMM: C[M,N] = A[M,K] @ W[N,K]^T ----------------
// m97 structure: 128x128 tile, BK=64, 256 threads (4 waves, 2x2 of 64x64),
// linear LDS + global_load_lds(16B), 2-barrier loop.
template<int OUT_BF16>
__global__ __launch_bounds__(256) void gemm128(const unsigned short* __restrict__ A,
                                               const unsigned short* __restrict__ W,
                                               unsigned short* __restrict__ Cb,
                                               float* __restrict__ Cf,
                                               int N, int K) {
    __shared__ unsigned short As[128 * 64];
    __shared__ unsigned short Bs[128 * 64];
    const int tid  = threadIdx.x;
    const int lane = tid & 63;
    const int wave = tid >> 6;
    const int bm = blockIdx.y * 128;
    const int bn = blockIdx.x * 128;
    const int wr = (wave >> 1) * 64;
    const int wc = (wave & 1) * 64;
    const int l15 = lane & 15;
    const int l4  = lane >> 4;

    // staging: wave w covers tile rows [w*32, w*32+32), 4 instrs x 8 rows each;
    // lane l -> row l>>3, col (l&7)*8 shorts (matches linear LDS base+lane*16B)
    const int srow = wave * 32 + (lane >> 3);
    const int scol = (lane & 7) * 8;
    const unsigned short* Ag = A + (size_t)(bm + srow) * K + scol;
    const unsigned short* Wg = W + (size_t)(bn + srow) * K + scol;
    unsigned short* Al = As + wave * 32 * 64;
    unsigned short* Bl = Bs + wave * 32 * 64;

    f32x4 acc[4][4];
#pragma unroll
    for (int i = 0; i < 4; ++i)
#pragma unroll
        for (int j = 0; j < 4; ++j) acc[i][j] = (f32x4){0.f, 0.f, 0.f, 0.f};

    for (int k0 = 0; k0 < K; k0 += 64) {
        __syncthreads();   // previous iteration's ds_reads done
#pragma unroll
        for (int i = 0; i < 4; ++i) {
            gload16(Ag + k0 + (size_t)(i * 8) * K, Al + i * 8 * 64);
            gload16(Wg + k0 + (size_t)(i * 8) * K, Bl + i * 8 * 64);
        }
        __syncthreads();   // drains vmcnt(0): staged data visible
#pragma unroll
        for (int kk = 0; kk < 2; ++kk) {
            short8 af[4], bf[4];
#pragma unroll
            for (int mi = 0; mi < 4; ++mi)
                af[mi] = *(const short8*)&As[(wr + mi * 16 + l15) * 64 + kk * 32 + l4 * 8];
#pragma unroll
            for (int ni = 0; ni < 4; ++ni)
                bf[ni] = *(const short8*)&Bs[(wc + ni * 16 + l15) * 64 + kk * 32 + l4 * 8];
#pragma unroll
            for (int mi = 0; mi < 4; ++mi)
#pragma unroll
                for (int ni = 0; ni < 4; ++ni)
                    acc[mi][ni] = __builtin_amdgcn_mfma_f32_16x16x32_bf16(af[mi], bf[ni], acc[mi][ni], 0, 0, 0);
        }
    }
    // epilogue: C/D layout col=lane&15, row=(lane>>4)*4+i (HW-verified)
#pragma unroll
    for (int mi = 0; mi < 4; ++mi)
#pragma unroll
        for (int ni = 0; ni < 4; ++ni)
#pragma unroll
            for (int i = 0; i < 4; ++i) {
                int row = bm + wr + mi * 16 + l4 * 4 + i;
                int col = bn + wc + ni * 16 + l15;
                float v = acc[mi][ni][i];
                if constexpr (OUT_BF16) Cb[(size_t)row * N + col] = f2b(v);
                else                    Cf[(size_t)row * N + col] = v;
            }
}

// ---------------- bf16 MFMA flash attention (causal) ----------------
// Block = (b, h, q-tile), LONGEST-FIRST: qt = 31 - blockIdx.x so the 32-tile
// blocks dispatch first and the tail is the ~1-tile blocks (round-8 lesson:
// ascending qt left the biggest blocks draining an idle GPU).
// 4 waves x 16 q-rows; QK^T and PV on mfma_f32_16x16x32_bf16.
// Q/K/V read from interleaved qkv[row][3072]; K, V^T staged in swizzled LDS.
__global__ __launch_bounds__(256) void attn_mfma(const unsigned short* __restrict__ Qp,
                                                 const unsigned short* __restrict__ Kp,
                                                 const unsigned short* __restrict__ Vp,
                                                 unsigned short* __restrict__ Yp) {
    __shared__ unsigned short Ks[64 * 64];     // K[key][d]
    __shared__ unsigned short Vt[64 * 64];     // V^T[d][key]
    __shared__ unsigned short Pl[4 * 16 * 64]; // per-wave P[q][key]
    const int tid  = threadIdx.x;
    const int lane = tid & 63;
    const int wq   = tid >> 6;
    const int l15  = lane & 15;
    const int l4   = lane >> 4;
    const int r    = tid >> 2;
    const int c4   = tid & 3;
    const int qt = (S_LEN / 64 - 1) - (int)blockIdx.x;   // longest-job-first
    const int h = blockIdx.y, b = blockIdx.z;
    unsigned short* Pw = Pl + wq * (16 * 64);

    short8 qf0, qf1;
    {
        const unsigned short* qb = Qp + ((size_t)(b * S_LEN + qt * 64 + wq * 16 + l15)) * QKV_LD
                                      + h * HDIM + l4 * 8;
        qf0 = *(const short8*)qb;
        qf1 = *(const short8*)(qb + 32);
    }
    f32x4 oacc[4];
    float mrow[4], lrow[4];
#pragma unroll
    for (int t = 0; t < 4; ++t) oacc[t] = (f32x4){0.f, 0.f, 0.f, 0.f};
#pragma unroll
    for (int i = 0; i < 4; ++i) { mrow[i] = -1e30f; lrow[i] = 0.f; }

#pragma unroll 1
    for (int kt = 0; kt <= qt; ++kt) {
        __syncthreads();
        {   // stage K tile + transposed V tile
            const size_t gb = ((size_t)(b * S_LEN + kt * 64 + r)) * QKV_LD + h * HDIM + c4 * 16;
            uint4 k0 = *(const uint4*)(Kp + gb);
            uint4 k1 = *(const uint4*)(Kp + gb + 8);
            uint4 v0 = *(const uint4*)(Vp + gb);
            uint4 v1 = *(const uint4*)(Vp + gb + 8);
            *(uint4*)swzp(Ks, r, c4 * 16)     = k0;
            *(uint4*)swzp(Ks, r, c4 * 16 + 8) = k1;
            const unsigned short* vs = (const unsigned short*)&v0;
#pragma unroll
            for (int j = 0; j < 8; ++j) *swzp(Vt, c4 * 16 + j, r) = vs[j];
            vs = (const unsigned short*)&v1;
#pragma unroll
            for (int j = 0; j < 8; ++j) *swzp(Vt, c4 * 16 + 8 + j, r) = vs[j];
        }
        __syncthreads();

        f32x4 sc[4];
#pragma unroll
        for (int t = 0; t < 4; ++t) sc[t] = (f32x4){0.f, 0.f, 0.f, 0.f};
#pragma unroll
        for (int t = 0; t < 4; ++t) {
            short8 kf = *(const short8*)swzp(Ks, t * 16 + l15, l4 * 8);
            sc[t] = __builtin_amdgcn_mfma_f32_16x16x32_bf16(qf0, kf, sc[t], 0, 0, 0);
        }
#pragma unroll
        for (int t = 0; t < 4; ++t) {
            short8 kf = *(const short8*)swzp(Ks, t * 16 + l15, 32 + l4 * 8);
            sc[t] = __builtin_amdgcn_mfma_f32_16x16x32_bf16(qf1, kf, sc[t], 0, 0, 0);
        }
        const bool diag = (kt == qt);
#pragma unroll
        for (int t = 0; t < 4; ++t)
#pragma unroll
            for (int i = 0; i < 4; ++i) {
                float s = sc[t][i] * 0.125f;
                if (diag && (t * 16 + l15 > wq * 16 + l4 * 4 + i)) s = -1e30f;
                sc[t][i] = s;
            }
#pragma unroll
        for (int i = 0; i < 4; ++i) {
            float mx = fmaxf(fmaxf(sc[0][i], sc[1][i]), fmaxf(sc[2][i], sc[3][i]));
            mx = fmaxf(mx, __shfl_xor(mx, 1));
            mx = fmaxf(mx, __shfl_xor(mx, 2));
            mx = fmaxf(mx, __shfl_xor(mx, 4));
            mx = fmaxf(mx, __shfl_xor(mx, 8));
            const float mn = fmaxf(mrow[i], mx);
            const float al = __expf(mrow[i] - mn);
            mrow[i] = mn;
            float ls = 0.f;
#pragma unroll
            for (int t = 0; t < 4; ++t) {
                float p = __expf(sc[t][i] - mn);
                sc[t][i] = p;
                ls += p;
            }
            ls += __shfl_xor(ls, 1);
            ls += __shfl_xor(ls, 2);
            ls += __shfl_xor(ls, 4);
            ls += __shfl_xor(ls, 8);
            lrow[i] = lrow[i] * al + ls;
#pragma unroll
            for (int t = 0; t < 4; ++t) oacc[t][i] *= al;
        }
#pragma unroll
        for (int t = 0; t < 4; ++t)
#pragma unroll
            for (int i = 0; i < 4; ++i)
                *swzp(Pw, l4 * 4 + i, t * 16 + l15) = f2b(sc[t][i]);

        short8 pf0 = *(const short8*)swzp(Pw, l15, l4 * 8);
        short8 pf1 = *(const short8*)swzp(Pw, l15, 32 + l4 * 8);
#pragma unroll
        for (int td = 0; td < 4; ++td) {
            short8 vf = *(const short8*)swzp(Vt, td * 16 + l15, l4 * 8);
            oacc[td] = __builtin_amdgcn_mfma_f32_16x16x32_bf16(pf0, vf, oacc[td], 0, 0, 0);
        }
#pragma unroll
        for (int td = 0; td < 4; ++td) {
            short8 vf = *(const short8*)swzp(Vt, td * 16 + l15, 32 + l4 * 8);
            oacc[td] = __builtin_amdgcn_mfma_f32_16x16x32_bf16(pf1, vf, oacc[td], 0, 0, 0);
        }
    }
    float linv[4];
#pragma unroll
    for (int i = 0; i < 4; ++i) linv[i] = 1.0f / lrow[i];
    unsigned short* yb = Yp + ((size_t)(b * S_LEN + qt * 64 + wq * 16 + l4 * 4)) * DMODEL
                            + h * HDIM + l15;
#pragma unroll
    for (int i = 0; i < 4; ++i)
#pragma unroll
        for (int td = 0; td < 4; ++td)
            yb[(size_t)i * DMODEL + td * 16] = f2b(oacc[td][i] * linv[i]);
}

extern "C" void kernel_launch(void* const* d_in, const int* in_sizes, int n_in,
                              void* d_out, int out_size, void* d_ws, size_t ws_size,
                              hipStream_t stream) {
    (void)in_sizes; (void)n_in; (void)out_size; (void)ws_size;
    const float* x  = (const float*)d_in[0];
    const float* Wq = (const float*)d_in[1];
    const float* Wk = (const float*)d_in[2];
    const float* Wv = (const float*)d_in[3];
    const float* Wo = (const float*)d_in[4];
    float* out = (float*)d_out;

    const size_t nx = (size_t)BATCH * S_LEN * DMODEL;   // 4,194,304
    const size_t nw = (size_t)DMODEL * DMODEL;          // 1,048,576
    char* ws = (char*)d_ws;
    unsigned short* xb    = (unsigned short*)ws; ws += nx * 2;          // 8 MB
    unsigned short* wqkvb = (unsigned short*)ws; ws += nw * 3 * 2;      // 6 MB (Wq|Wk|Wv rows)
    unsigned short* wob   = (unsigned short*)ws; ws += nw * 2;          // 2 MB (contiguous after wqkvb)
    unsigned short* qkv   = (unsigned short*)ws; ws += nx * 3 * 2;      // 24 MB [row][3072]
    unsigned short* yb    = (unsigned short*)ws; ws += nx * 2;          // 8 MB  -> 48 MB total

    cast_kernel<<<(int)(nx / 4 + 255) / 256, 256, 0, stream>>>(x, xb, (int)(nx / 4));
    cast_w4<<<(1 << 20) / 256, 256, 0, stream>>>(Wq, Wk, Wv, Wo, wqkvb);  // dest = wqkv|wo

    dim3 gq(QKV_LD / 128, (BATCH * S_LEN) / 128);   // 24 x 32
    gemm128<1><<<gq, 256, 0, stream>>>(xb, wqkvb, qkv, nullptr, QKV_LD, DMODEL);

    dim3 ga(S_LEN / 64, NHEADS, BATCH);             // 32 x 16 x 2 = 1024 blocks
    attn_mfma<<<ga, 256, 0, stream>>>(qkv, qkv + DMODEL, qkv + 2 * DMODEL, yb);

    dim3 go(DMODEL / 128, (BATCH * S_LEN) / 128);   // 8 x 32
    gemm128<0><<<go, 256, 0, stream>>>(yb, wob, nullptr, out, DMODEL, DMODEL);
}

// Round 11
// 231.267 us; speedup vs baseline: 1.2674x; 1.2622x over previous
//
#include <hip/hip_runtime.h>
#include <hip/hip_bf16.h>

// TinySelfAttention: x[2,2048,1024] fp32; Wq/Wk/Wv/Wo [1024,1024] fp32 ([out,in]).
// out = softmax_causal((xWq^T)(xWk^T)^T/8) (xWv^T) Wo^T, fp32.
//
// Pipeline: cast x -> bf16, cast 4 W -> bf16 | fused QKV MFMA GEMM (128^2,
// global_load_lds, Q pre-scaled 1/8) -> qkv[row][3072] | bf16 MFMA flash attn
// (folded q-tile pairs, K/V double-buffered LDS, 1 barrier/iter, reg prefetch)
// -> y bf16 | MFMA GEMM y@Wo^T -> fp32 out.

#define S_LEN  2048
#define BATCH  2
#define DMODEL 1024
#define NHEADS 16
#define HDIM   64
#define QKV_LD 3072

typedef short short8 __attribute__((ext_vector_type(8)));
typedef float f32x4  __attribute__((ext_vector_type(4)));

__device__ __forceinline__ float b2f(unsigned short u) {
    union { unsigned int i; float f; } x; x.i = ((unsigned int)u) << 16; return x.f;
}
__device__ __forceinline__ unsigned short f2b(float f) {
    union { float f; unsigned int i; } x; x.f = f;
    unsigned int r = x.i + 0x7fffu + ((x.i >> 16) & 1u);  // RNE
    return (unsigned short)(r >> 16);
}

// async global->LDS, 16B per lane; LDS dest = wave-uniform base + lane*16 (HW rule)
__device__ __forceinline__ void gload16(const unsigned short* g, unsigned short* l) {
    __builtin_amdgcn_global_load_lds(
        (const __attribute__((address_space(1))) unsigned int*)g,
        (__attribute__((address_space(3))) unsigned int*)l, 16, 0, 0);
}

// XOR-swizzled accessor for 128B-row LDS tiles (attn; G4 bank-conflict fix).
__device__ __forceinline__ unsigned short* swzp(unsigned short* base, int row, int col) {
    int byte = (col << 1) ^ ((((row >> 3) ^ row) & 7) << 4);
    return base + (row << 6) + (byte >> 1);
}

// ---------------- cast fp32 -> bf16, 4 elems/thread ----------------
__global__ void cast_kernel(const float* __restrict__ in, unsigned short* __restrict__ out, int n4) {
    int i = blockIdx.x * blockDim.x + threadIdx.x;
    if (i >= n4) return;
    float4 v = ((const float4*)in)[i];
    unsigned int lo = (unsigned int)f2b(v.x) | ((unsigned int)f2b(v.y) << 16);
    unsigned int hi = (unsigned int)f2b(v.z) | ((unsigned int)f2b(v.w) << 16);
    ((uint2*)out)[i] = make_uint2(lo, hi);
}

// cast 4 weights (1M floats each) into one contiguous bf16 dest (wqkv | wo)
__global__ void cast_w4(const float* __restrict__ w0, const float* __restrict__ w1,
                        const float* __restrict__ w2, const float* __restrict__ w3,
                        unsigned short* __restrict__ out) {
    int i = blockIdx.x * blockDim.x + threadIdx.x;     // over 4M/4 = 1M float4
    if (i >= (1 << 20)) return;
    int seg = i >> 18;                                 // 2^18 float4 per weight
    const float* src = seg == 0 ? w0 : seg == 1 ? w1 : seg == 2 ? w2 : w3;
    float4 v = ((const float4*)src)[i & 0x3FFFF];
    unsigned int lo = (unsigned int)f2b(v.x) | ((unsigned int)f2b(v.y) << 16);
    unsigned int hi = (unsigned int)f2b(v.z) | ((unsigned int)f2b(v.w) << 16);
    ((uint2*)out)[i] = make_uint2(lo, hi);
}

// ---------------- bf16 MFMA GEMM: C[M,N] = A[M,K] @ W[N,K]^T ----------------
// m97 structure: 128x128 tile, BK=64, 256 threads (4 waves, 2x2 of 64x64),
// linear LDS + global_load_lds(16B), 2-barrier loop.
// OUT_BF16==1 (QKV gemm): cols < DMODEL (the Q block) are pre-scaled by 1/8.
template<int OUT_BF16>
__global__ __launch_bounds__(256) void gemm128(const unsigned short* __restrict__ A,
                                               const unsigned short* __restrict__ W,
                                               unsigned short* __restrict__ Cb,
                                               float* __restrict__ Cf,
                                               int N, int K) {
    __shared__ unsigned short As[128 * 64];
    __shared__ unsigned short Bs[128 * 64];
    const int tid  = threadIdx.x;
    const int lane = tid & 63;
    const int wave = tid >> 6;
    const int bm = blockIdx.y * 128;
    const int bn = blockIdx.x * 128;
    const int wr = (wave >> 1) * 64;
    const int wc = (wave & 1) * 64;
    const int l15 = lane & 15;
    const int l4  = lane >> 4;

    const int srow = wave * 32 + (lane >> 3);
    const int scol = (lane & 7) * 8;
    const unsigned short* Ag = A + (size_t)(bm + srow) * K + scol;
    const unsigned short* Wg = W + (size_t)(bn + srow) * K + scol;
    unsigned short* Al = As + wave * 32 * 64;
    unsigned short* Bl = Bs + wave * 32 * 64;

    f32x4 acc[4][4];
#pragma unroll
    for (int i = 0; i < 4; ++i)
#pragma unroll
        for (int j = 0; j < 4; ++j) acc[i][j] = (f32x4){0.f, 0.f, 0.f, 0.f};

    for (int k0 = 0; k0 < K; k0 += 64) {
        __syncthreads();   // previous iteration's ds_reads done
#pragma unroll
        for (int i = 0; i < 4; ++i) {
            gload16(Ag + k0 + (size_t)(i * 8) * K, Al + i * 8 * 64);
            gload16(Wg + k0 + (size_t)(i * 8) * K, Bl + i * 8 * 64);
        }
        __syncthreads();   // drains vmcnt(0): staged data visible
#pragma unroll
        for (int kk = 0; kk < 2; ++kk) {
            short8 af[4], bf[4];
#pragma unroll
            for (int mi = 0; mi < 4; ++mi)
                af[mi] = *(const short8*)&As[(wr + mi * 16 + l15) * 64 + kk * 32 + l4 * 8];
#pragma unroll
            for (int ni = 0; ni < 4; ++ni)
                bf[ni] = *(const short8*)&Bs[(wc + ni * 16 + l15) * 64 + kk * 32 + l4 * 8];
#pragma unroll
            for (int mi = 0; mi < 4; ++mi)
#pragma unroll
                for (int ni = 0; ni < 4; ++ni)
                    acc[mi][ni] = __builtin_amdgcn_mfma_f32_16x16x32_bf16(af[mi], bf[ni], acc[mi][ni], 0, 0, 0);
        }
    }
    // epilogue: C/D layout col=lane&15, row=(lane>>4)*4+i (HW-verified)
#pragma unroll
    for (int mi = 0; mi < 4; ++mi)
#pragma unroll
        for (int ni = 0; ni < 4; ++ni)
#pragma unroll
            for (int i = 0; i < 4; ++i) {
                int row = bm + wr + mi * 16 + l4 * 4 + i;
                int col = bn + wc + ni * 16 + l15;
                float v = acc[mi][ni][i];
                if constexpr (OUT_BF16) {
                    if (col < DMODEL) v *= 0.125f;   // pre-scale Q (exact pow2)
                    Cb[(size_t)row * N + col] = f2b(v);
                } else {
                    Cf[(size_t)row * N + col] = v;
                }
            }
}

// ---------------- bf16 MFMA flash attention (causal) ----------------
// Block = (b, h, folded q-tile pair {f, 31-f}): 512 blocks, uniform 33 kv-tiles
// (round-8/9 lesson: homogeneous blocks beat any unfolded schedule).
// K/V double-buffered in LDS -> ONE barrier per kv-tile; next tile's global
// loads issued into registers right after this tile's LDS writes (T14 split),
// hiding HBM/L3 latency under MFMA+softmax.
// 4 waves x 16 q-rows. Q is pre-scaled by 1/8 in the QKV GEMM.
__global__ __launch_bounds__(256) void attn_mfma(const unsigned short* __restrict__ Qp,
                                                 const unsigned short* __restrict__ Kp,
                                                 const unsigned short* __restrict__ Vp,
                                                 unsigned short* __restrict__ Yp) {
    __shared__ unsigned short Ks[2][64 * 64];  // K[key][d], double-buffered
    __shared__ unsigned short Vt[2][64 * 64];  // V^T[d][key], double-buffered
    __shared__ unsigned short Pl[4 * 16 * 64]; // per-wave P[q][key]
    const int tid  = threadIdx.x;
    const int lane = tid & 63;
    const int wq   = tid >> 6;
    const int l15  = lane & 15;
    const int l4   = lane >> 4;
    const int r    = tid >> 2;
    const int c4   = tid & 3;
    const int h = blockIdx.y, b = blockIdx.z;
    unsigned short* Pw = Pl + wq * (16 * 64);

#pragma unroll 1
    for (int qp = 0; qp < 2; ++qp) {
        const int qt = qp ? (31 - (int)blockIdx.x) : (int)blockIdx.x;
        short8 qf0, qf1;
        {
            const unsigned short* qb = Qp + ((size_t)(b * S_LEN + qt * 64 + wq * 16 + l15)) * QKV_LD
                                          + h * HDIM + l4 * 8;
            qf0 = *(const short8*)qb;
            qf1 = *(const short8*)(qb + 32);
        }
        f32x4 oacc[4];
        float mrow[4], lrow[4];
#pragma unroll
        for (int t = 0; t < 4; ++t) oacc[t] = (f32x4){0.f, 0.f, 0.f, 0.f};
#pragma unroll
        for (int i = 0; i < 4; ++i) { mrow[i] = -1e30f; lrow[i] = 0.f; }

        // prologue: load kv-tile 0 into registers
        uint4 rk0, rk1, rv0, rv1;
        {
            const size_t gb = ((size_t)(b * S_LEN + r)) * QKV_LD + h * HDIM + c4 * 16;
            rk0 = *(const uint4*)(Kp + gb);
            rk1 = *(const uint4*)(Kp + gb + 8);
            rv0 = *(const uint4*)(Vp + gb);
            rv1 = *(const uint4*)(Vp + gb + 8);
        }

#pragma unroll 1
        for (int kt = 0; kt <= qt; ++kt) {
            const int cur = kt & 1;
            unsigned short* Kc = (unsigned short*)Ks[cur];
            unsigned short* Vc = (unsigned short*)Vt[cur];
            // write staged registers to LDS buf `cur` (other waves may still be
            // computing on buf cur^1 -- different buffer, safe; all reads of
            // buf cur finished before the previous iteration's barrier)
            *(uint4*)swzp(Kc, r, c4 * 16)     = rk0;
            *(uint4*)swzp(Kc, r, c4 * 16 + 8) = rk1;
            {
                const unsigned short* vs = (const unsigned short*)&rv0;
#pragma unroll
                for (int j = 0; j < 8; ++j) *swzp(Vc, c4 * 16 + j, r) = vs[j];
                vs = (const unsigned short*)&rv1;
#pragma unroll
                for (int j = 0; j < 8; ++j) *swzp(Vc, c4 * 16 + 8 + j, r) = vs[j];
            }
            // prefetch next kv-tile into registers; latency hides under compute
            if (kt < qt) {
                const size_t gb = ((size_t)(b * S_LEN + (kt + 1) * 64 + r)) * QKV_LD
                                  + h * HDIM + c4 * 16;
                rk0 = *(const uint4*)(Kp + gb);
                rk1 = *(const uint4*)(Kp + gb + 8);
                rv0 = *(const uint4*)(Vp + gb);
                rv1 = *(const uint4*)(Vp + gb + 8);
            }
            __syncthreads();   // buf `cur` visible to all waves

            f32x4 sc[4];
#pragma unroll
            for (int t = 0; t < 4; ++t) sc[t] = (f32x4){0.f, 0.f, 0.f, 0.f};
#pragma unroll
            for (int t = 0; t < 4; ++t) {
                short8 kf = *(const short8*)swzp(Kc, t * 16 + l15, l4 * 8);
                sc[t] = __builtin_amdgcn_mfma_f32_16x16x32_bf16(qf0, kf, sc[t], 0, 0, 0);
            }
#pragma unroll
            for (int t = 0; t < 4; ++t) {
                short8 kf = *(const short8*)swzp(Kc, t * 16 + l15, 32 + l4 * 8);
                sc[t] = __builtin_amdgcn_mfma_f32_16x16x32_bf16(qf1, kf, sc[t], 0, 0, 0);
            }
            const bool diag = (kt == qt);
#pragma unroll
            for (int t = 0; t < 4; ++t)
#pragma unroll
                for (int i = 0; i < 4; ++i) {
                    float s = sc[t][i];   // Q pre-scaled by 1/8 in GEMM
                    if (diag && (t * 16 + l15 > wq * 16 + l4 * 4 + i)) s = -1e30f;
                    sc[t][i] = s;
                }
#pragma unroll
            for (int i = 0; i < 4; ++i) {
                float mx = fmaxf(fmaxf(sc[0][i], sc[1][i]), fmaxf(sc[2][i], sc[3][i]));
                mx = fmaxf(mx, __shfl_xor(mx, 1));
                mx = fmaxf(mx, __shfl_xor(mx, 2));
                mx = fmaxf(mx, __shfl_xor(mx, 4));
                mx = fmaxf(mx, __shfl_xor(mx, 8));
                const float mn = fmaxf(mrow[i], mx);
                const float al = __expf(mrow[i] - mn);
                mrow[i] = mn;
                float ls = 0.f;
#pragma unroll
                for (int t = 0; t < 4; ++t) {
                    float p = __expf(sc[t][i] - mn);
                    sc[t][i] = p;
                    ls += p;
                }
                ls += __shfl_xor(ls, 1);
                ls += __shfl_xor(ls, 2);
                ls += __shfl_xor(ls, 4);
                ls += __shfl_xor(ls, 8);
                lrow[i] = lrow[i] * al + ls;
#pragma unroll
                for (int t = 0; t < 4; ++t) oacc[t][i] *= al;
            }
#pragma unroll
            for (int t = 0; t < 4; ++t)
#pragma unroll
                for (int i = 0; i < 4; ++i)
                    *swzp(Pw, l4 * 4 + i, t * 16 + l15) = f2b(sc[t][i]);

            short8 pf0 = *(const short8*)swzp(Pw, l15, l4 * 8);
            short8 pf1 = *(const short8*)swzp(Pw, l15, 32 + l4 * 8);
#pragma unroll
            for (int td = 0; td < 4; ++td) {
                short8 vf = *(const short8*)swzp(Vc, td * 16 + l15, l4 * 8);
                oacc[td] = __builtin_amdgcn_mfma_f32_16x16x32_bf16(pf0, vf, oacc[td], 0, 0, 0);
            }
#pragma unroll
            for (int td = 0; td < 4; ++td) {
                short8 vf = *(const short8*)swzp(Vc, td * 16 + l15, 32 + l4 * 8);
                oacc[td] = __builtin_amdgcn_mfma_f32_16x16x32_bf16(pf1, vf, oacc[td], 0, 0, 0);
            }
        }
        __syncthreads();   // qp=1 reuses buf 0: wait for all waves' last compute

        float linv[4];
#pragma unroll
        for (int i = 0; i < 4; ++i) linv[i] = 1.0f / lrow[i];
        unsigned short* yb = Yp + ((size_t)(b * S_LEN + qt * 64 + wq * 16 + l4 * 4)) * DMODEL
                                + h * HDIM + l15;
#pragma unroll
        for (int i = 0; i < 4; ++i)
#pragma unroll
            for (int td = 0; td < 4; ++td)
                yb[(size_t)i * DMODEL + td * 16] = f2b(oacc[td][i] * linv[i]);
    }
}

extern "C" void kernel_launch(void* const* d_in, const int* in_sizes, int n_in,
                              void* d_out, int out_size, void* d_ws, size_t ws_size,
                              hipStream_t stream) {
    (void)in_sizes; (void)n_in; (void)out_size; (void)ws_size;
    const float* x  = (const float*)d_in[0];
    const float* Wq = (const float*)d_in[1];
    const float* Wk = (const float*)d_in[2];
    const float* Wv = (const float*)d_in[3];
    const float* Wo = (const float*)d_in[4];
    float* out = (float*)d_out;

    const size_t nx = (size_t)BATCH * S_LEN * DMODEL;   // 4,194,304
    const size_t nw = (size_t)DMODEL * DMODEL;          // 1,048,576
    char* ws = (char*)d_ws;
    unsigned short* xb    = (unsigned short*)ws; ws += nx * 2;          // 8 MB
    unsigned short* wqkvb = (unsigned short*)ws; ws += nw * 3 * 2;      // 6 MB (Wq|Wk|Wv rows)
    unsigned short* wob   = (unsigned short*)ws; ws += nw * 2;          // 2 MB (contiguous after wqkvb)
    unsigned short* qkv   = (unsigned short*)ws; ws += nx * 3 * 2;      // 24 MB [row][3072]
    unsigned short* yb    = (unsigned short*)ws; ws += nx * 2;          // 8 MB  -> 48 MB total

    cast_kernel<<<(int)(nx / 4 + 255) / 256, 256, 0, stream>>>(x, xb, (int)(nx / 4));
    cast_w4<<<(1 << 20) / 256, 256, 0, stream>>>(Wq, Wk, Wv, Wo, wqkvb);  // dest = wqkv|wo

    dim3 gq(QKV_LD / 128, (BATCH * S_LEN) / 128);   // 24 x 32
    gemm128<1><<<gq, 256, 0, stream>>>(xb, wqkvb, qkv, nullptr, QKV_LD, DMODEL);

    dim3 ga(S_LEN / 128, NHEADS, BATCH);            // 16 folded q-tile pairs = 512 blocks
    attn_mfma<<<ga, 256, 0, stream>>>(qkv, qkv + DMODEL, qkv + 2 * DMODEL, yb);

    dim3 go(DMODEL / 128, (BATCH * S_LEN) / 128);   // 8 x 32
    gemm128<0><<<go, 256, 0, stream>>>(yb, wob, nullptr, out, DMODEL, DMODEL);
}